// Round 5
// baseline (410.053 us; speedup 1.0000x reference)
//
#include <hip/hip_runtime.h>
#include <hip/hip_bf16.h>
#include <stdint.h>

#define D_MODEL 1024
#define NHEAD   16
#define DK      64
#define BATCH   4
#define SEQ     2048
#define MROWS   (BATCH*SEQ)   // 8192

typedef __hip_bfloat16 bf16;
typedef __attribute__((ext_vector_type(8))) short short8;
typedef __attribute__((ext_vector_type(4))) float f32x4;
typedef __attribute__((ext_vector_type(4))) unsigned int uint4t;

typedef __attribute__((address_space(1))) unsigned int as1_uint;
typedef __attribute__((address_space(3))) unsigned int as3_uint;

#define MFMA32(a,b,c) __builtin_amdgcn_mfma_f32_16x16x32_bf16((a),(b),(c),0,0,0)

static __device__ __forceinline__ void load_lds16(const bf16* g, bf16* l) {
  __builtin_amdgcn_global_load_lds((const as1_uint*)g, (as3_uint*)l, 16, 0, 0);
}

static __device__ __forceinline__ unsigned short bfbits(float x) {
  __hip_bfloat16 h = __float2bfloat16(x);
  return __builtin_bit_cast(unsigned short, h);
}

// RNE pack via software (host-side-ish paths)
static __device__ __forceinline__ unsigned int pack2(float lo, float hi) {
  return (unsigned int)bfbits(lo) | ((unsigned int)bfbits(hi) << 16);
}

// HW RNE pack: v_cvt_pk_bf16_f32 (gfx950; no builtin — T12/m240 recipe).
// D[15:0]=bf16(lo), D[31:16]=bf16(hi).
static __device__ __forceinline__ unsigned int cvtpk(float lo, float hi) {
  unsigned int d;
  asm("v_cvt_pk_bf16_f32 %0, %1, %2" : "=v"(d) : "v"(lo), "v"(hi));
  return d;
}

// truncation pack: ~1 VALU inst (v_perm). P in [0,1]; bias cancels because
// lsum is computed from the SAME truncated fragments (consistent weights).
static __device__ __forceinline__ unsigned int pack2t(float lo, float hi) {
  return (__builtin_bit_cast(unsigned int, lo) >> 16) |
         (__builtin_bit_cast(unsigned int, hi) & 0xffff0000u);
}

// ---------------------------------------------------------------- cast kernel (weights only; cast_x folded into gemm_proj)
__global__ __launch_bounds__(256) void cast_w(const float* __restrict__ i0,
                                              const float* __restrict__ i1,
                                              const float* __restrict__ i2,
                                              const float* __restrict__ i3,
                                              bf16* o0, bf16* o1, bf16* o2, bf16* o3,
                                              float s1) {
  const int z = blockIdx.z;
  const float* in = z == 0 ? i0 : (z == 1 ? i1 : (z == 2 ? i2 : i3));
  bf16* out = z == 0 ? o0 : (z == 1 ? o1 : (z == 2 ? o2 : o3));
  const float s = (z == 1) ? s1 : 1.0f;
  int i = blockIdx.x * 256 + threadIdx.x;
  const float4* p = (const float4*)in;
  float4 a = p[2 * (size_t)i];
  float4 b = p[2 * (size_t)i + 1];
  uint4t u;
  u.x = pack2(a.x * s, a.y * s);
  u.y = pack2(a.z * s, a.w * s);
  u.z = pack2(b.x * s, b.y * s);
  u.w = pack2(b.z * s, b.w * s);
  *(uint4t*)(out + (size_t)i * 8) = u;
}

// ------------------------------------------------------------ shared GEMM loop pieces
#define GEMM_STAGE(BUFOFF, KT) do {                                   \
    load_lds16(Ag0 + (KT), As + (BUFOFF) + w * 512);                  \
    load_lds16(Ag1 + (KT), As + (BUFOFF) + 2048 + w * 512);           \
    load_lds16(Bg0 + (KT), Bs + (BUFOFF) + w * 512);                  \
    load_lds16(Bg1 + (KT), Bs + (BUFOFF) + 2048 + w * 512);           \
  } while (0)

#define GEMM_COMPUTE(BUFOFF) do {                                              \
    short8 af[4], bf_[4];                                                      \
    _Pragma("unroll") for (int i = 0; i < 4; ++i) {                            \
      af[i]  = *(const short8*)(As + (BUFOFF) + (wm + i * 16 + lm) * 32 + lq * 8); \
      bf_[i] = *(const short8*)(Bs + (BUFOFF) + (wn + i * 16 + lm) * 32 + lq * 8); \
    }                                                                          \
    _Pragma("unroll") for (int i = 0; i < 4; ++i)                              \
      _Pragma("unroll") for (int j = 0; j < 4; ++j)                            \
        acc[i][j] = MFMA32(af[i], bf_[j], acc[i][j]);                          \
  } while (0)

#define VMCNT0_BAR() do {                                   \
    asm volatile("s_waitcnt vmcnt(0)" ::: "memory");        \
    __syncthreads();                                        \
  } while (0)

// ---------------------------------------------------------------- projection GEMMs
// fp32 A read directly (cast_x deleted): A reg-staged as 4x dwordx4 fp32 ->
// 8x v_cvt_pk_bf16_f32 -> 2x ds_write_b128 into the SAME linear LDS layout
// the old global_load_lds produced. Loads issue before compute (latency
// hidden); cvt+write lands in the other dbuf half after compute (no
// conflict with concurrent readers of the current half). B (bf16 weights)
// stays on global_load_lds. VALUBusy was 13% -> plenty of headroom.
#define PROJ_LOADA(KT) do {                                  \
    ar0 = *(const float4*)(Af0 + (KT));                      \
    ar1 = *(const float4*)(Af0 + (KT) + 4);                  \
    ar2 = *(const float4*)(Af1 + (KT));                      \
    ar3 = *(const float4*)(Af1 + (KT) + 4);                  \
  } while (0)

#define PROJ_STOREA(BUFOFF) do {                             \
    uint4t u0, u1;                                           \
    u0.x = cvtpk(ar0.x, ar0.y); u0.y = cvtpk(ar0.z, ar0.w);  \
    u0.z = cvtpk(ar1.x, ar1.y); u0.w = cvtpk(ar1.z, ar1.w);  \
    u1.x = cvtpk(ar2.x, ar2.y); u1.y = cvtpk(ar2.z, ar2.w);  \
    u1.z = cvtpk(ar3.x, ar3.y); u1.w = cvtpk(ar3.z, ar3.w);  \
    *(uint4t*)(As + (BUFOFF) + t * 8) = u0;                  \
    *(uint4t*)(As + (BUFOFF) + 2048 + t * 8) = u1;           \
  } while (0)

#define PROJ_STAGEB(BUFOFF, KT) do {                                  \
    load_lds16(Bg0 + (KT), Bs + (BUFOFF) + w * 512);                  \
    load_lds16(Bg1 + (KT), Bs + (BUFOFF) + 2048 + w * 512);           \
  } while (0)

__global__ __launch_bounds__(256) void gemm_proj(const float* __restrict__ A0,
                                                 const float* __restrict__ A1,
                                                 const float* __restrict__ A2,
                                                 const bf16* __restrict__ B0,
                                                 const bf16* __restrict__ B1,
                                                 const bf16* __restrict__ B2,
                                                 bf16* C0, bf16* C1, bf16* C2) {
  const int z = blockIdx.z;
  const float* A = z == 0 ? A0 : (z == 1 ? A1 : A2);
  const bf16* B = z == 0 ? B0 : (z == 1 ? B1 : B2);
  bf16* C = z == 0 ? C0 : (z == 1 ? C1 : C2);
  const int M = MROWS, N = D_MODEL, K = D_MODEL;

  __shared__ bf16 As[2 * 128 * 32];
  __shared__ bf16 Bs[2 * 128 * 32];
  const int t = threadIdx.x;
  const int w = t >> 6;
  const int lane = t & 63;
  const int lm = lane & 15;
  const int lq = lane >> 4;
  const int wm = (w >> 1) * 64;
  const int wn = (w & 1) * 64;
  const long rowA = (long)blockIdx.x * 128;   // M-tile (grid transposed: id%8 = mTile%8 -> XCD L2 reuse)
  const long rowB = (long)blockIdx.y * 128;   // N-tile

  const int srow = t >> 2;
  const int scol = (t & 3) * 8;
  const float* Af0 = A + (rowA + srow) * K + scol;
  const float* Af1 = A + (rowA + 64 + srow) * K + scol;
  const bf16* Bg0 = B + (rowB + srow) * K + scol;
  const bf16* Bg1 = B + (rowB + 64 + srow) * K + scol;

  float4 ar0, ar1, ar2, ar3;

  const f32x4 fzero = {0.f, 0.f, 0.f, 0.f};
  f32x4 acc[4][4];
#pragma unroll
  for (int i = 0; i < 4; ++i)
#pragma unroll
    for (int j = 0; j < 4; ++j) acc[i][j] = fzero;

  PROJ_LOADA(0);
  PROJ_STAGEB(0, 0);
  PROJ_STOREA(0);          // compiler waits the fp32 loads; ds_writes drain at the barrier
  VMCNT0_BAR();            // B's global_load_lds done
  for (int kt = 0; kt < K; kt += 64) {
    if (kt + 32 < K) { PROJ_LOADA(kt + 32); PROJ_STAGEB(4096, kt + 32); }
    GEMM_COMPUTE(0);
    asm volatile("s_waitcnt vmcnt(0)" ::: "memory");
    if (kt + 32 < K) PROJ_STOREA(4096);
    __syncthreads();
    if (kt + 64 < K) { PROJ_LOADA(kt + 64); PROJ_STAGEB(0, kt + 64); }
    GEMM_COMPUTE(4096);
    asm volatile("s_waitcnt vmcnt(0)" ::: "memory");
    if (kt + 64 < K) PROJ_STOREA(0);
    __syncthreads();
  }

  if (z < 2) {
#pragma unroll
    for (int i = 0; i < 4; ++i) {
      long r0 = rowA + wm + i * 16 + lq * 4;
#pragma unroll
      for (int j = 0; j < 4; ++j) {
        long c = rowB + wn + j * 16 + lm;
#pragma unroll
        for (int r = 0; r < 4; ++r)
          C[(r0 + r) * N + c] = __float2bfloat16(acc[i][j][r]);
      }
    }
  } else {
    // Vt[d][s'] with s' kv-interleaved: s=tile*64+half*16+m -> s'=tile*64+m*2+half
#pragma unroll
    for (int j = 0; j < 4; ++j) {
      long c = rowB + wn + j * 16 + lm;  // d
#pragma unroll
      for (int i = 0; i < 4; ++i) {
        long r0 = rowA + wm + i * 16 + lq * 4;  // s base, 4 consecutive
        long sp = (r0 & ~63L) | (((r0 >> 5) & 1) * 32) | ((r0 & 15) * 2) | ((r0 >> 4) & 1);
#pragma unroll
        for (int r = 0; r < 4; ++r)
          C[c * M + sp + r * 2] = __float2bfloat16(acc[i][j][r]);
      }
    }
  }
}

// ---------------------------------------------------------------- output GEMM (+bias, fp32 out)
__global__ __launch_bounds__(256) void gemm_out(const bf16* __restrict__ A,
                                                const bf16* __restrict__ B,
                                                float* __restrict__ C,
                                                const float* __restrict__ bias) {
  const int M = MROWS, N = D_MODEL, K = D_MODEL;
  __shared__ bf16 As[2 * 128 * 32];
  __shared__ bf16 Bs[2 * 128 * 32];
  const int t = threadIdx.x;
  const int w = t >> 6;
  const int lane = t & 63;
  const int lm = lane & 15;
  const int lq = lane >> 4;
  const int wm = (w >> 1) * 64;
  const int wn = (w & 1) * 64;
  const long rowA = (long)blockIdx.x * 128;   // M-tile (grid transposed)
  const long rowB = (long)blockIdx.y * 128;   // N-tile

  const int srow = t >> 2;
  const int scol = (t & 3) * 8;
  const bf16* Ag0 = A + (rowA + srow) * K + scol;
  const bf16* Ag1 = A + (rowA + 64 + srow) * K + scol;
  const bf16* Bg0 = B + (rowB + srow) * K + scol;
  const bf16* Bg1 = B + (rowB + 64 + srow) * K + scol;

  const f32x4 fzero = {0.f, 0.f, 0.f, 0.f};
  f32x4 acc[4][4];
#pragma unroll
  for (int i = 0; i < 4; ++i)
#pragma unroll
    for (int j = 0; j < 4; ++j) acc[i][j] = fzero;

  GEMM_STAGE(0, 0);
  VMCNT0_BAR();
  for (int kt = 0; kt < K; kt += 64) {
    if (kt + 32 < K) GEMM_STAGE(4096, kt + 32);
    GEMM_COMPUTE(0);
    VMCNT0_BAR();
    if (kt + 64 < K) GEMM_STAGE(0, kt + 64);
    GEMM_COMPUTE(4096);
    VMCNT0_BAR();
  }

#pragma unroll
  for (int j = 0; j < 4; ++j) {
    long c = rowB + wn + j * 16 + lm;
    float bz = bias[c];
#pragma unroll
    for (int i = 0; i < 4; ++i) {
      long r0 = rowA + wm + i * 16 + lq * 4;
#pragma unroll
      for (int r = 0; r < 4; ++r)
        C[(r0 + r) * N + c] = acc[i][j][r] + bz;
    }
  }
}

// ---------------------------------------------------------------- flash attention v6
// v5 + double-buffered K/V staging (same recipe as the GEMMs): stage tile t+1
// into the other 16KB half before compute of t; one vmcnt(0)+barrier per tile.
// LDS 16->32KB, still 4 blocks/CU. Attacks the ~9% non-busy sliver
// (MfmaUtil 44.8 + VALUBusy 46.5 = 91% in R3).
#define ATTN_STAGE(BUF) do {                                 \
    load_lds16(kg0, Ks + (BUF) + w * 512);                   \
    load_lds16(kg1, Ks + (BUF) + 2048 + w * 512);            \
    load_lds16(vg0, Vs + (BUF) + w * 512);                   \
    load_lds16(vg1, Vs + (BUF) + 2048 + w * 512);            \
    kg0 += 64 * D_MODEL; kg1 += 64 * D_MODEL;                \
    vg0 += 64; vg1 += 64;                                    \
  } while (0)

#define ATTN_COMPUTE(BUF) do {                                                       \
    short8 kf[4][2];                                                                 \
    _Pragma("unroll") for (int c = 0; c < 4; ++c)                                    \
      _Pragma("unroll") for (int ks = 0; ks < 2; ++ks)                               \
        kf[c][ks] = *(const short8*)(Ks + (BUF) + (c * 16 + lm) * 64 + (((ks * 4 + lq) ^ xs) * 8)); \
    short8 vf[4][2];                                                                 \
    _Pragma("unroll") for (int dt = 0; dt < 4; ++dt)                                 \
      _Pragma("unroll") for (int tt = 0; tt < 2; ++tt)                               \
        vf[dt][tt] = *(const short8*)(Vs + (BUF) + (dt * 16 + lm) * 64 + (((tt * 4 + lq) ^ xs) * 8)); \
    _Pragma("unroll") for (int qt = 0; qt < 2; ++qt) {                               \
      f32x4 st[4];                                                                   \
      _Pragma("unroll") for (int c = 0; c < 4; ++c)                                  \
        st[c] = MFMA32(kf[c][0], qf[qt][0], fzero);                                  \
      _Pragma("unroll") for (int c = 0; c < 4; ++c)                                  \
        st[c] = MFMA32(kf[c][1], qf[qt][1], st[c]);                                  \
      float pe[4][4];                                                                \
      _Pragma("unroll") for (int c = 0; c < 4; ++c)                                  \
        _Pragma("unroll") for (int r = 0; r < 4; ++r)                                \
          pe[c][r] = __builtin_amdgcn_exp2f(st[c][r]);                               \
      short8 pf8[2];                                                                 \
      _Pragma("unroll") for (int tt = 0; tt < 2; ++tt) {                             \
        uint4t u;                                                                    \
        u.x = pack2t(pe[2 * tt][0], pe[2 * tt + 1][0]);                              \
        u.y = pack2t(pe[2 * tt][1], pe[2 * tt + 1][1]);                              \
        u.z = pack2t(pe[2 * tt][2], pe[2 * tt + 1][2]);                              \
        u.w = pack2t(pe[2 * tt][3], pe[2 * tt + 1][3]);                              \
        pf8[tt] = __builtin_bit_cast(short8, u);                                     \
      }                                                                              \
      _Pragma("unroll") for (int tt = 0; tt < 2; ++tt) {                             \
        lsum[qt] = MFMA32(pf8[tt], ones8, lsum[qt]);                                 \
        _Pragma("unroll") for (int dt = 0; dt < 4; ++dt)                             \
          O[qt][dt] = MFMA32(pf8[tt], vf[dt][tt], O[qt][dt]);                        \
      }                                                                              \
    }                                                                                \
  } while (0)

__global__ __launch_bounds__(256, 4) void attn_kernel(const bf16* __restrict__ Qb,
                                                      const bf16* __restrict__ Kb,
                                                      const bf16* __restrict__ Vt,
                                                      bf16* __restrict__ ctx) {
  __shared__ bf16 Ks[2 * 64 * 64];
  __shared__ bf16 Vs[2 * 64 * 64];
  const int t = threadIdx.x;
  const int w = t >> 6;
  const int lane = t & 63;
  const int lm = lane & 15;
  const int lq = lane >> 4;
  const int bh = blockIdx.x;
  const int b = bh >> 4;
  const int h = bh & 15;
  const int q0 = blockIdx.y * 128 + w * 32;

  const bf16* Qh = Qb + (long)b * SEQ * D_MODEL + h * DK;
  const bf16* Kh = Kb + (long)b * SEQ * D_MODEL + h * DK;
  const bf16* Vh = Vt + (long)h * DK * MROWS + (long)b * SEQ;

  const int sr = lane >> 3;
  const int sc = ((lane & 7) ^ sr) * 8;      // XOR-swizzled staging column
  const bf16* kg0 = Kh + (long)(w * 8 + sr) * D_MODEL + sc;
  const bf16* kg1 = Kh + (long)(32 + w * 8 + sr) * D_MODEL + sc;
  const bf16* vg0 = Vh + (long)(w * 8 + sr) * MROWS + sc;
  const bf16* vg1 = Vh + (long)(32 + w * 8 + sr) * MROWS + sc;

  short8 qf[2][2];
#pragma unroll
  for (int qt = 0; qt < 2; ++qt)
#pragma unroll
    for (int ks = 0; ks < 2; ++ks)
      qf[qt][ks] = *(const short8*)(Qh + (long)(q0 + qt * 16 + lm) * D_MODEL + ks * 32 + lq * 8);

  uint4t uo;
  uo.x = 0x3F803F80u; uo.y = 0x3F803F80u; uo.z = 0x3F803F80u; uo.w = 0x3F803F80u;
  const short8 ones8 = __builtin_bit_cast(short8, uo);

  const f32x4 fzero = {0.f, 0.f, 0.f, 0.f};
  f32x4 O[2][4];
  f32x4 lsum[2];
#pragma unroll
  for (int qt = 0; qt < 2; ++qt) {
    lsum[qt] = fzero;
#pragma unroll
    for (int dt = 0; dt < 4; ++dt) O[qt][dt] = fzero;
  }

  const int xs = lm & 7;

  ATTN_STAGE(0);
  VMCNT0_BAR();
  for (int kv = 0; kv < SEQ; kv += 128) {
    if (kv + 64 < SEQ) ATTN_STAGE(4096);
    ATTN_COMPUTE(0);
    VMCNT0_BAR();
    if (kv + 128 < SEQ) ATTN_STAGE(0);
    ATTN_COMPUTE(4096);
    VMCNT0_BAR();
  }

#pragma unroll
  for (int qt = 0; qt < 2; ++qt) {
    f32x4 linv;
#pragma unroll
    for (int r = 0; r < 4; ++r) linv[r] = 1.f / lsum[qt][r];
#pragma unroll
    for (int r = 0; r < 4; ++r) {
      long qrow = (long)b * SEQ + q0 + qt * 16 + lq * 4 + r;
#pragma unroll
      for (int dt = 0; dt < 4; ++dt)
        ctx[qrow * D_MODEL + h * DK + dt * 16 + lm] =
            __float2bfloat16(O[qt][dt][r] * linv[r]);
    }
  }
}

// ---------------------------------------------------------------- launch
extern "C" void kernel_launch(void* const* d_in, const int* in_sizes, int n_in,
                              void* d_out, int out_size, void* d_ws, size_t ws_size,
                              hipStream_t stream) {
  const float* q  = (const float*)d_in[0];
  const float* k  = (const float*)d_in[1];
  const float* v  = (const float*)d_in[2];
  const float* wq = (const float*)d_in[3];
  const float* wk = (const float*)d_in[4];
  const float* wv = (const float*)d_in[5];
  const float* wo = (const float*)d_in[6];
  const float* bo = (const float*)d_in[7];

  char* ws = (char*)d_ws;
  const size_t SZW = (size_t)D_MODEL * D_MODEL * sizeof(bf16);  // 2 MB
  const size_t SZX = (size_t)MROWS * D_MODEL * sizeof(bf16);    // 16.78 MB
  bf16* Wq = (bf16*)(ws + 0 * SZW);
  bf16* Wk = (bf16*)(ws + 1 * SZW);
  bf16* Wv = (bf16*)(ws + 2 * SZW);
  bf16* Wo = (bf16*)(ws + 3 * SZW);
  bf16* Vt = (bf16*)(ws + 4 * SZW + 0 * SZX);
  bf16* Cx = (bf16*)(ws + 4 * SZW + 1 * SZX);
  bf16* Qb = (bf16*)(ws + 4 * SZW + 3 * SZX);
  bf16* Kb = (bf16*)(ws + 4 * SZW + 4 * SZX);

  const float SCL = 0.18033688011112042f;  // (1/sqrt(64)) * log2(e), folded into Wk
  const int NW8 = D_MODEL * D_MODEL / 8;

  cast_w<<<dim3(NW8 / 256, 1, 4), 256, 0, stream>>>(wq, wk, wv, wo, Wq, Wk, Wv, Wo, SCL);

  // fp32 activations consumed directly (cast folded into A staging)
  gemm_proj<<<dim3(MROWS / 128, D_MODEL / 128, 3), 256, 0, stream>>>(
      q, k, v, Wq, Wk, Wv, Qb, Kb, Vt);

  attn_kernel<<<dim3(BATCH * NHEAD, SEQ / 128), 256, 0, stream>>>(Qb, Kb, Vt, Cx);

  gemm_out<<<dim3(MROWS / 128, D_MODEL / 128), 256, 0, stream>>>(Cx, Wo, (float*)d_out, bo);
}